// Round 5
// baseline (528.708 us; speedup 1.0000x reference)
//
#include <hip/hip_runtime.h>

// RF grid-sample DAS beamforming.
// Shapes: d_tx[4,512,256] d_rx[128,512,256] apod[128,512,256] rf[4,128,3072] t0[4]
// out[4,512,256] fp32.
//
// R5. History: R0=93us (TPB=512, 2 blk/CU, scalar stream loads, 64 VGPR, zero
// headroom). R1=120us (angle split: occupancy up, amortization down). R3=121us
// (fp16-dup LDS halves conflicts -- confirmed, kept -- but reg-prefetch spilled).
// R4=275us (launch_bounds(512,6) VGPR cap 84 -> compiler allocated 40, spilled
// acc/dta + rematerialized loads: FETCH 320MB / WRITE 207MB scratch traffic).
//
// R5 = R4's layout with a register budget that holds the live state:
//  - TPB=256 (4 waves), 48KB LDS -> 3 blocks/CU (12 waves), launch_bounds(256,3)
//    -> VGPR cap 168; live state ~80 floats fits with headroom. No spills.
//  - PXT=8 CONTIGUOUS pixels/thread: drx/apod = 2 float4 loads per e-iter
//    (issued BEFORE the barrier; HBM latency hides under staging), d_tx = 2
//    float4 per angle. Stream-load instructions per iter: 16 scalar -> 4 vec.
//  - rf staging: 12 float4 loads (LLC-resident) issued as one batch.
//  - fp16 DUPLICATED pairs in LDS: lds[s]={rf[s],rf[s+1]} 4B -> one
//    ds_read_b32 per interp; conflicts halve (measured R3). RNE converts.
//  - Amortization invariants of R0 preserved (4 angles, same total staging /
//    stream / atomic traffic).
// Partial sums across 16 e-chunks via fp32 atomicAdd (out zeroed by memset;
// graph-capture safe).
// Data range: delay in [0,3070] => i1 <= 3071 = S-1: clamp is no-op safety;
// duplicated pair at s=3071 (garbage second half) is never read.

#define A_N 4
#define E_N 128
#define S_N 3072
#define NPIX_N (512 * 256)
#define TPB 256                    // threads per block (4 waves)
#define PXT 8                      // contiguous pixels per thread
#define TILE (TPB * PXT)           // 2048 pixels per block
#define TILES (NPIX_N / TILE)      // 64
#define ESPLIT 16                  // e-chunks
#define EPB (E_N / ESPLIT)         // 8 elements per block
#define SIT ((A_N * (S_N / 4)) / TPB)  // 3072 float4-slots / 256 thr = 12

typedef __fp16 half2_t __attribute__((ext_vector_type(2)));

__global__ __launch_bounds__(TPB, 3) void das_kernel(
    const float* __restrict__ d_tx, const float* __restrict__ d_rx,
    const float* __restrict__ apod, const float* __restrict__ rf,
    const float* __restrict__ t0,  float* __restrict__ out)
{
    __shared__ __align__(16) half2_t lds_rf[A_N * S_N];   // 48 KB
    const int tid = threadIdx.x;
    const int px0 = blockIdx.x * TILE + tid * PXT;   // 8 contiguous pixels
    const int e0  = blockIdx.y * EPB;

    float acc[A_N][PXT];
    float dta[A_N][PXT];
#pragma unroll
    for (int a = 0; a < A_N; ++a) {
        const float t0a = t0[a];
        float4 v0 = *(const float4*)(d_tx + a * NPIX_N + px0);
        float4 v1 = *(const float4*)(d_tx + a * NPIX_N + px0 + 4);
        dta[a][0] = v0.x - t0a; dta[a][1] = v0.y - t0a;
        dta[a][2] = v0.z - t0a; dta[a][3] = v0.w - t0a;
        dta[a][4] = v1.x - t0a; dta[a][5] = v1.y - t0a;
        dta[a][6] = v1.z - t0a; dta[a][7] = v1.w - t0a;
#pragma unroll
        for (int k = 0; k < PXT; ++k) acc[a][k] = 0.0f;
    }

    for (int ei = 0; ei < EPB; ++ei) {
        const int e = e0 + ei;
        // Stream loads issued before the barrier (no LDS dependency):
        // HBM latency hides under barrier + staging below.
        const float4 drxA = *(const float4*)(d_rx + (size_t)e * NPIX_N + px0);
        const float4 drxB = *(const float4*)(d_rx + (size_t)e * NPIX_N + px0 + 4);
        const float4 apA  = *(const float4*)(apod + (size_t)e * NPIX_N + px0);
        const float4 apB  = *(const float4*)(apod + (size_t)e * NPIX_N + px0 + 4);

        __syncthreads();   // previous iteration's gathers done before overwrite
#pragma unroll
        for (int j = 0; j < SIT; ++j) {
            int idx = tid + j * TPB;          // float4 slot 0..3071
            int a   = idx / (S_N / 4);        // 0..3
            int s4  = idx - a * (S_N / 4);    // 0..767
            const float* r = rf + a * (E_N * S_N) + e * S_N + s4 * 4;
            float4 v = *(const float4*)r;
            float  x = r[(s4 == (S_N / 4 - 1)) ? 3 : 4];  // clamped; pair at 3071 never read
            union { half2_t h[4]; float4 f; } u;
            u.h[0] = half2_t{(__fp16)v.x, (__fp16)v.y};   // RNE converts
            u.h[1] = half2_t{(__fp16)v.y, (__fp16)v.z};
            u.h[2] = half2_t{(__fp16)v.z, (__fp16)v.w};
            u.h[3] = half2_t{(__fp16)v.w, (__fp16)x};
            *(float4*)&lds_rf[a * S_N + s4 * 4] = u.f;
        }
        __syncthreads();

        float drx[PXT], ap[PXT];
        drx[0]=drxA.x; drx[1]=drxA.y; drx[2]=drxA.z; drx[3]=drxA.w;
        drx[4]=drxB.x; drx[5]=drxB.y; drx[6]=drxB.z; drx[7]=drxB.w;
        ap[0]=apA.x; ap[1]=apA.y; ap[2]=apA.z; ap[3]=apA.w;
        ap[4]=apB.x; ap[5]=apB.y; ap[6]=apB.z; ap[7]=apB.w;

#pragma unroll
        for (int k = 0; k < PXT; ++k) {
#pragma unroll
            for (int a = 0; a < A_N; ++a) {
                float delay = dta[a][k] + drx[k];
                float x0 = floorf(delay);
                float w  = delay - x0;
                int i0 = (int)x0;
                i0 = min(max(i0, 0), S_N - 2);   // no-op for this data; safety
                half2_t hv = lds_rf[a * S_N + i0];   // one ds_read_b32: {v0,v1}
                float v0 = (float)hv[0];
                float v1 = (float)hv[1];
                acc[a][k] += (v0 + w * (v1 - v0)) * ap[k];
            }
        }
    }

#pragma unroll
    for (int a = 0; a < A_N; ++a)
#pragma unroll
        for (int k = 0; k < PXT; ++k)
            atomicAdd(&out[a * NPIX_N + px0 + k], acc[a][k]);
}

extern "C" void kernel_launch(void* const* d_in, const int* in_sizes, int n_in,
                              void* d_out, int out_size, void* d_ws, size_t ws_size,
                              hipStream_t stream) {
    const float* d_tx = (const float*)d_in[0];
    const float* d_rx = (const float*)d_in[1];
    const float* apod = (const float*)d_in[2];
    const float* rf   = (const float*)d_in[3];
    const float* t0   = (const float*)d_in[4];
    float* out = (float*)d_out;

    hipMemsetAsync(out, 0, (size_t)out_size * sizeof(float), stream);
    dim3 grid(TILES, ESPLIT);
    das_kernel<<<grid, TPB, 0, stream>>>(d_tx, d_rx, apod, rf, t0, out);
}

// Round 6
// 508.188 us; speedup vs baseline: 1.0404x; 1.0404x over previous
//
#include <hip/hip_runtime.h>

// RF grid-sample DAS beamforming.
// Shapes: d_tx[4,512,256] d_rx[128,512,256] apod[128,512,256] rf[4,128,3072] t0[4]
// out[4,512,256] fp32.
//
// R6. Ladder so far: R0=93us (clean: VGPR 64, FETCH 91MB, WRITE 33MB).
// R1=120us (angle split: amortization loss). R3=121us (fp16-dup LDS GOOD:
// conflicts 1.04e7->5.2e6 measured; but reg-prefetch spilled). R4=275us,
// R5=421us (register-budget experiments; allocator spills instead of using
// headroom: FETCH/WRITE ballooned to 288/327MB).
// META-LESSON: allocator refuses >~84 VGPR here; only R0's shape (TPB=512,
// bounds(512,2), VGPR=64) is spill-free. So R6 = R0's exact structure +
// only zero-live-state changes:
//  - fp16 DUPLICATED pairs in LDS: lds[s]={rf[s],rf[s+1]} packed half2 (4B).
//    One ds_read_b32 per interp instead of two; bank conflicts halve
//    (counter-verified in R3). RNE converts for precision margin.
//    Transient staging temps only; nothing new lives across barriers.
//  - CONTIGUOUS 8 px/thread + float4 stream loads placed at R0's position
//    (top of compute phase, after the barrier): 16 scalar drx/ap loads ->
//    4 dwordx4 per e-iter; d_tx init 8 float4s; atomics per-lane contiguous.
//    Same register lifetime as R0 (values were live there too).
// Spill litmus for post-mortem: FETCH ~91MB, WRITE ~33MB, VGPR 64-80.
// Partial sums across 16 e-chunks via fp32 atomicAdd (out zeroed by memset;
// graph-capture safe).
// Data range: delay in [0,3070] => i1 <= 3071 = S-1: clamp is no-op safety;
// duplicated pair at s=3071 (garbage second half) is never read.

#define A_N 4
#define E_N 128
#define S_N 3072
#define NPIX_N (512 * 256)
#define TPB 512                    // threads per block (8 waves)
#define PXT 8                      // contiguous pixels per thread
#define TILE (TPB * PXT)           // 4096 pixels per block
#define TILES (NPIX_N / TILE)      // 32
#define ESPLIT 16                  // e-chunks
#define EPB (E_N / ESPLIT)         // 8 elements per block
#define SIT ((A_N * (S_N / 4)) / TPB)  // 3072 float4-slots / 512 thr = 6

typedef __fp16 half2_t __attribute__((ext_vector_type(2)));

__global__ __launch_bounds__(TPB, 2) void das_kernel(
    const float* __restrict__ d_tx, const float* __restrict__ d_rx,
    const float* __restrict__ apod, const float* __restrict__ rf,
    const float* __restrict__ t0,  float* __restrict__ out)
{
    __shared__ __align__(16) half2_t lds_rf[A_N * S_N];   // 48 KB
    const int tid = threadIdx.x;
    const int px0 = blockIdx.x * TILE + tid * PXT;   // 8 contiguous pixels
    const int e0  = blockIdx.y * EPB;

    float acc[A_N][PXT];
    float dta[A_N][PXT];
#pragma unroll
    for (int a = 0; a < A_N; ++a) {
        const float t0a = t0[a];
        float4 v0 = *(const float4*)(d_tx + a * NPIX_N + px0);
        float4 v1 = *(const float4*)(d_tx + a * NPIX_N + px0 + 4);
        dta[a][0] = v0.x - t0a; dta[a][1] = v0.y - t0a;
        dta[a][2] = v0.z - t0a; dta[a][3] = v0.w - t0a;
        dta[a][4] = v1.x - t0a; dta[a][5] = v1.y - t0a;
        dta[a][6] = v1.z - t0a; dta[a][7] = v1.w - t0a;
#pragma unroll
        for (int k = 0; k < PXT; ++k) acc[a][k] = 0.0f;
    }

    for (int ei = 0; ei < EPB; ++ei) {
        const int e = e0 + ei;
        __syncthreads();   // previous iteration's gathers done before overwrite
        // Stage rf[a][e][:] for all 4 angles as duplicated fp16 pairs.
#pragma unroll
        for (int j = 0; j < SIT; ++j) {
            int idx = tid + j * TPB;          // float4 slot 0..3071
            int a   = idx / (S_N / 4);        // 0..3
            int s4  = idx - a * (S_N / 4);    // 0..767
            const float* r = rf + a * (E_N * S_N) + e * S_N + s4 * 4;
            float4 v = *(const float4*)r;
            float  x = r[(s4 == (S_N / 4 - 1)) ? 3 : 4];  // clamped; pair at 3071 never read
            union { half2_t h[4]; float4 f; } u;
            u.h[0] = half2_t{(__fp16)v.x, (__fp16)v.y};   // RNE converts
            u.h[1] = half2_t{(__fp16)v.y, (__fp16)v.z};
            u.h[2] = half2_t{(__fp16)v.z, (__fp16)v.w};
            u.h[3] = half2_t{(__fp16)v.w, (__fp16)x};
            *(float4*)&lds_rf[a * S_N + s4 * 4] = u.f;
        }
        __syncthreads();

        // Stream loads at R0's position (short register lifetime), but
        // vectorized: 4 dwordx4 instead of 16 scalar loads.
        const float4 drxA = *(const float4*)(d_rx + (size_t)e * NPIX_N + px0);
        const float4 drxB = *(const float4*)(d_rx + (size_t)e * NPIX_N + px0 + 4);
        const float4 apA  = *(const float4*)(apod + (size_t)e * NPIX_N + px0);
        const float4 apB  = *(const float4*)(apod + (size_t)e * NPIX_N + px0 + 4);
        float drx[PXT], ap[PXT];
        drx[0]=drxA.x; drx[1]=drxA.y; drx[2]=drxA.z; drx[3]=drxA.w;
        drx[4]=drxB.x; drx[5]=drxB.y; drx[6]=drxB.z; drx[7]=drxB.w;
        ap[0]=apA.x;  ap[1]=apA.y;  ap[2]=apA.z;  ap[3]=apA.w;
        ap[4]=apB.x;  ap[5]=apB.y;  ap[6]=apB.z;  ap[7]=apB.w;

#pragma unroll
        for (int k = 0; k < PXT; ++k) {
#pragma unroll
            for (int a = 0; a < A_N; ++a) {
                float delay = dta[a][k] + drx[k];
                float x0 = floorf(delay);
                float w  = delay - x0;
                int i0 = (int)x0;
                i0 = min(max(i0, 0), S_N - 2);   // no-op for this data; safety
                half2_t hv = lds_rf[a * S_N + i0];   // one ds_read_b32: {v0,v1}
                float v0 = (float)hv[0];
                float v1 = (float)hv[1];
                acc[a][k] += (v0 + w * (v1 - v0)) * ap[k];
            }
        }
    }

#pragma unroll
    for (int a = 0; a < A_N; ++a)
#pragma unroll
        for (int k = 0; k < PXT; ++k)
            atomicAdd(&out[a * NPIX_N + px0 + k], acc[a][k]);
}

extern "C" void kernel_launch(void* const* d_in, const int* in_sizes, int n_in,
                              void* d_out, int out_size, void* d_ws, size_t ws_size,
                              hipStream_t stream) {
    const float* d_tx = (const float*)d_in[0];
    const float* d_rx = (const float*)d_in[1];
    const float* apod = (const float*)d_in[2];
    const float* rf   = (const float*)d_in[3];
    const float* t0   = (const float*)d_in[4];
    float* out = (float*)d_out;

    hipMemsetAsync(out, 0, (size_t)out_size * sizeof(float), stream);
    dim3 grid(TILES, ESPLIT);
    das_kernel<<<grid, TPB, 0, stream>>>(d_tx, d_rx, apod, rf, t0, out);
}

// Round 7
// 235.481 us; speedup vs baseline: 2.2452x; 2.1581x over previous
//
#include <hip/hip_runtime.h>

// RF grid-sample DAS beamforming.
// Shapes: d_tx[4,512,256] d_rx[128,512,256] apod[128,512,256] rf[4,128,3072] t0[4]
// out[4,512,256] fp32.
//
// R7 = R0's exact structure + fp16-dup LDS ONLY.
// Ladder: R0=93us (clean: VGPR 64, FETCH 91MB, WRITE 33MB, conflicts 1.04e7).
//   R1=120 (angle split: amortization loss). R3=121 (fp16-dup verified:
//   conflicts -> 5.2e6, but reg-prefetch spilled). R4/R5=275/421 (reg-budget
//   experiments -> spills). R6=400 (CONTIGUOUS-per-thread pixels: atomic
//   lanes strided 32B -> 2 lanes/64B-sector -> 4.2M sector write-throughs =
//   262MB WRITE, 8x atomic serialization; lesson: keep R0's lane-contiguous
//   stride-TPB addressing for streams AND atomics).
//
// The one kept change vs R0: rf staged in LDS as DUPLICATED fp16 pairs,
// lds[s] = {rf[s], rf[s+1]} packed half2 (4B). One ds_read_b32 per interp
// instead of two b32 reads -> LDS gather instructions halve and bank
// conflicts halve (counter-verified in R3). RNE converts; per-tap err ~3e-4,
// random-walk over 128 elements stays well under the 0.0625 tolerance
// (R3/R6 passed with absmax 0.125 vs allowed threshold).
// No register prefetch (R3's spill cause), no float4 stream batching (R6's
// VGPR creep): scalar stream loads are already dense 256B/wave-instruction.
//
// Spill/layout litmus: VGPR ~64, FETCH ~91MB, WRITE ~33MB.
// Partial sums across 16 e-chunks via fp32 atomicAdd (out zeroed by memset;
// graph-capture safe).
// Data range: delay in [0,3070] => i1 <= 3071 = S-1: clamp is no-op safety;
// duplicated pair at s=3071 (garbage second half) is never read.

#define A_N 4
#define E_N 128
#define S_N 3072
#define NPIX_N (512 * 256)
#define TPB 512                    // threads per block (8 waves)
#define PXT 8                      // pixels per thread (stride-TPB)
#define TILE (TPB * PXT)           // 4096 pixels per block
#define TILES (NPIX_N / TILE)      // 32
#define ESPLIT 16                  // e-chunks
#define EPB (E_N / ESPLIT)         // 8 elements per block
#define SIT ((A_N * (S_N / 4)) / TPB)  // 3072 float4-slots / 512 thr = 6

typedef __fp16 half2_t __attribute__((ext_vector_type(2)));

__global__ __launch_bounds__(TPB, 2) void das_kernel(
    const float* __restrict__ d_tx, const float* __restrict__ d_rx,
    const float* __restrict__ apod, const float* __restrict__ rf,
    const float* __restrict__ t0,  float* __restrict__ out)
{
    __shared__ __align__(16) half2_t lds_rf[A_N * S_N];   // 48 KB
    const int tid = threadIdx.x;
    const int px0 = blockIdx.x * TILE + tid;   // + k*TPB for k in [0,PXT)
    const int e0  = blockIdx.y * EPB;

    float acc[A_N][PXT];
    float dta[A_N][PXT];
#pragma unroll
    for (int a = 0; a < A_N; ++a) {
        const float t0a = t0[a];
#pragma unroll
        for (int k = 0; k < PXT; ++k) {
            dta[a][k] = d_tx[a * NPIX_N + px0 + k * TPB] - t0a;
            acc[a][k] = 0.0f;
        }
    }

    for (int ei = 0; ei < EPB; ++ei) {
        const int e = e0 + ei;
        __syncthreads();   // previous iteration's gathers done before overwrite
        // Stage rf[a][e][:] for all 4 angles as duplicated fp16 pairs.
#pragma unroll
        for (int j = 0; j < SIT; ++j) {
            int idx = tid + j * TPB;          // float4 slot 0..3071
            int a   = idx / (S_N / 4);        // 0..3
            int s4  = idx - a * (S_N / 4);    // 0..767
            const float* r = rf + a * (E_N * S_N) + e * S_N + s4 * 4;
            float4 v = *(const float4*)r;
            float  x = r[(s4 == (S_N / 4 - 1)) ? 3 : 4];  // clamped; pair at 3071 never read
            union { half2_t h[4]; float4 f; } u;
            u.h[0] = half2_t{(__fp16)v.x, (__fp16)v.y};   // RNE converts
            u.h[1] = half2_t{(__fp16)v.y, (__fp16)v.z};
            u.h[2] = half2_t{(__fp16)v.z, (__fp16)v.w};
            u.h[3] = half2_t{(__fp16)v.w, (__fp16)x};
            *(float4*)&lds_rf[a * S_N + s4 * 4] = u.f;
        }
        __syncthreads();

        const float* __restrict__ drx_row = d_rx + (size_t)e * NPIX_N;
        const float* __restrict__ ap_row  = apod + (size_t)e * NPIX_N;
#pragma unroll
        for (int k = 0; k < PXT; ++k) {
            const int p = px0 + k * TPB;
            const float drx = drx_row[p];     // dense 256B per wave-instruction
            const float ap  = ap_row[p];
#pragma unroll
            for (int a = 0; a < A_N; ++a) {
                float delay = dta[a][k] + drx;
                float x0 = floorf(delay);
                float w  = delay - x0;
                int i0 = (int)x0;
                i0 = min(max(i0, 0), S_N - 2);   // no-op for this data; safety
                half2_t hv = lds_rf[a * S_N + i0];   // one ds_read_b32: {v0,v1}
                float v0 = (float)hv[0];
                float v1 = (float)hv[1];
                acc[a][k] += (v0 + w * (v1 - v0)) * ap;
            }
        }
    }

#pragma unroll
    for (int a = 0; a < A_N; ++a)
#pragma unroll
        for (int k = 0; k < PXT; ++k)
            atomicAdd(&out[a * NPIX_N + px0 + k * TPB], acc[a][k]);
}

extern "C" void kernel_launch(void* const* d_in, const int* in_sizes, int n_in,
                              void* d_out, int out_size, void* d_ws, size_t ws_size,
                              hipStream_t stream) {
    const float* d_tx = (const float*)d_in[0];
    const float* d_rx = (const float*)d_in[1];
    const float* apod = (const float*)d_in[2];
    const float* rf   = (const float*)d_in[3];
    const float* t0   = (const float*)d_in[4];
    float* out = (float*)d_out;

    hipMemsetAsync(out, 0, (size_t)out_size * sizeof(float), stream);
    dim3 grid(TILES, ESPLIT);
    das_kernel<<<grid, TPB, 0, stream>>>(d_tx, d_rx, apod, rf, t0, out);
}

// Round 8
// 193.966 us; speedup vs baseline: 2.7258x; 1.2140x over previous
//
#include <hip/hip_runtime.h>

// RF grid-sample DAS beamforming.
// Shapes: d_tx[4,512,256] d_rx[128,512,256] apod[128,512,256] rf[4,128,3072] t0[4]
// out[4,512,256] fp32.
//
// R8: async double-buffered staging. Ladder: R0=93us (2 barriers/e-iter,
// lockstep phases, ~60% stall). R1=120 (angle split). R3/R4/R5 (any added
// live registers at 2-block occupancy -> spills). R6=400 (per-thread-contig
// atomics: 8x sector ops). R7=127 (fp16-dup LDS: conflicts halved, NO
// speedup -> LDS pipe was never critical; falsified).
//
// Structure:
//  - rf staged via __builtin_amdgcn_global_load_lds (DMA, zero VGPR, counted
//    by vmcnt) into a 2 x 48KB fp32 double buffer (96KB LDS).
//  - Per e-iter: issue next-e DMA -> stream loads -> interp on current buffer
//    -> ONE __syncthreads() (its implicit vmcnt(0)+lgkmcnt(0) drain is the
//    DMA completion wait; prefetch had the whole compute phase to land).
//    Staging latency fully hidden; barriers per iter: 2 -> 1.
//  - 96KB LDS => exactly 1 block/CU independent of VGPRs: register pressure
//    is FREE (escapes the R3/R4/R5 spill trap).
//  - ESPLIT 16->8: grid = 32x8 = 256 blocks = 1/CU exactly; atomic partials
//    per output halve (WRITE ~16MB).
//  - R0's lane-contiguous stride-TPB addressing kept for d_tx/d_rx/apod
//    loads and atomics (R6 lesson: 16 lanes/64B sector).
// Spill litmus: FETCH ~95MB, WRITE ~16-20MB even if VGPR is high.
// Partial sums across 8 e-chunks via fp32 atomicAdd (out zeroed by memset;
// graph-capture safe).
// Data range: delay in [0,3070] => i1 <= 3071 = S-1: clamp is no-op safety.

#define A_N 4
#define E_N 128
#define S_N 3072
#define NPIX_N (512 * 256)
#define TPB 512                    // threads per block (8 waves)
#define PXT 8                      // pixels per thread (stride-TPB)
#define TILE (TPB * PXT)           // 4096 pixels per block
#define TILES (NPIX_N / TILE)      // 32
#define ESPLIT 8                   // e-chunks
#define EPB (E_N / ESPLIT)         // 16 elements per block
#define CPA (S_N / 256)            // 12 1KB-chunks per angle row (12KB)
#define CHUNKS (A_N * CPA)         // 48 chunks per buffer
#define WAVES (TPB / 64)           // 8
#define CPW (CHUNKS / WAVES)       // 6 chunks per wave

__device__ __forceinline__ void ld_lds16(const float* g, float* l) {
    // 64 lanes x 16B: global (per-lane addr) -> LDS (wave-uniform base,
    // HW adds lane*16). size must be a literal 16.
    __builtin_amdgcn_global_load_lds(
        (const __attribute__((address_space(1))) void*)g,
        (__attribute__((address_space(3))) void*)l, 16, 0, 0);
}

__global__ __launch_bounds__(TPB, 2) void das_kernel(
    const float* __restrict__ d_tx, const float* __restrict__ d_rx,
    const float* __restrict__ apod, const float* __restrict__ rf,
    const float* __restrict__ t0,  float* __restrict__ out)
{
    __shared__ float lds_rf[2][A_N * S_N];   // 96 KB double buffer
    const int tid  = threadIdx.x;
    const int wid  = tid >> 6;
    const int lane = tid & 63;
    const int px0  = blockIdx.x * TILE + tid;   // + k*TPB for k in [0,PXT)
    const int e0   = blockIdx.y * EPB;

    // Issue async DMA of rf[a][e][:] (all 4 angles, 48KB) into buffer b.
    auto stage = [&](int b, int e) {
#pragma unroll
        for (int j = 0; j < CPW; ++j) {
            const int chunk = wid * CPW + j;        // 0..47, wave-uniform
            const int a = chunk / CPA;              // 0..3
            const int c = chunk - a * CPA;          // 0..11
            const float* g = rf + ((size_t)(a * E_N + e)) * S_N + c * 256 + lane * 4;
            float* l = &lds_rf[b][a * S_N + c * 256];
            ld_lds16(g, l);
        }
    };

    stage(0, e0);   // prologue DMA starts immediately

    float acc[A_N][PXT];
    float dta[A_N][PXT];
#pragma unroll
    for (int a = 0; a < A_N; ++a) {
        const float t0a = t0[a];
#pragma unroll
        for (int k = 0; k < PXT; ++k) {
            dta[a][k] = d_tx[a * NPIX_N + px0 + k * TPB] - t0a;
            acc[a][k] = 0.0f;
        }
    }

    __syncthreads();   // drains vmcnt: prologue DMA complete, block-wide

    for (int ei = 0; ei < EPB; ++ei) {
        const int e   = e0 + ei;
        const int cur = ei & 1;

        // Prefetch next element into the other buffer (async; that buffer's
        // readers all passed the barrier that ended iter ei-1).
        if (ei + 1 < EPB) stage(cur ^ 1, e + 1);

        const float* __restrict__ drx_row = d_rx + (size_t)e * NPIX_N;
        const float* __restrict__ ap_row  = apod + (size_t)e * NPIX_N;
        const float* __restrict__ L = lds_rf[cur];

#pragma unroll
        for (int k = 0; k < PXT; ++k) {
            const int p = px0 + k * TPB;
            const float drx = drx_row[p];     // dense 256B per wave-instruction
            const float ap  = ap_row[p];
#pragma unroll
            for (int a = 0; a < A_N; ++a) {
                float delay = dta[a][k] + drx;
                float x0 = floorf(delay);
                float w  = delay - x0;
                int i0 = (int)x0;
                i0 = min(max(i0, 0), S_N - 2);   // no-op for this data; safety
                float v0 = L[a * S_N + i0];
                float v1 = L[a * S_N + i0 + 1];
                acc[a][k] += (v0 + w * (v1 - v0)) * ap;
            }
        }

        // Single barrier per iter: implicit s_waitcnt vmcnt(0) lgkmcnt(0)
        // (HIP __syncthreads semantics) = DMA-completion wait for buf[cur^1],
        // and release of buf[cur] for the next prefetch.
        __syncthreads();
    }

#pragma unroll
    for (int a = 0; a < A_N; ++a)
#pragma unroll
        for (int k = 0; k < PXT; ++k)
            atomicAdd(&out[a * NPIX_N + px0 + k * TPB], acc[a][k]);
}

extern "C" void kernel_launch(void* const* d_in, const int* in_sizes, int n_in,
                              void* d_out, int out_size, void* d_ws, size_t ws_size,
                              hipStream_t stream) {
    const float* d_tx = (const float*)d_in[0];
    const float* d_rx = (const float*)d_in[1];
    const float* apod = (const float*)d_in[2];
    const float* rf   = (const float*)d_in[3];
    const float* t0   = (const float*)d_in[4];
    float* out = (float*)d_out;

    hipMemsetAsync(out, 0, (size_t)out_size * sizeof(float), stream);
    dim3 grid(TILES, ESPLIT);
    das_kernel<<<grid, TPB, 0, stream>>>(d_tx, d_rx, apod, rf, t0, out);
}

// Round 9
// 180.851 us; speedup vs baseline: 2.9234x; 1.0725x over previous
//
#include <hip/hip_runtime.h>

// RF grid-sample DAS beamforming.
// Shapes: d_tx[4,512,256] d_rx[128,512,256] apod[128,512,256] rf[4,128,3072] t0[4]
// out[4,512,256] fp32.
//
// R9 = R8 (83.5us, validated async-DMA double-buffer, 1 barrier/iter, clean
// at VGPR 112) + two TLP/ILP levers:
//  - TPB 512->1024 (PXT 8->4, TILE=4096, grid 32x8 = 1 block/CU): 16 waves/CU
//    instead of 8. LDS 96KB still caps at 1 block => registers remain free up
//    to the 4-wave/SIMD cap (128 VGPR).
//  - T14 stream prefetch (zero spill cost at 1 block/CU): at top of iter ei,
//    issue iter ei+1's drx/ap loads into registers; compute iter ei entirely
//    from registers. The end-of-iter __syncthreads (implicit vmcnt(0)) is the
//    completion wait for BOTH the DMA prefetch and the stream prefetch.
//    => interp loop has zero memory dependencies: pure LDS+VALU, and all
//    memory latency hides under it.
// History lessons baked in: lane-contiguous stride-TPB addressing everywhere
// (R6: contig-per-thread atomics = 8x sector ops); no fp16-dup (R7: LDS pipe
// not critical at this structure; DMA can't convert anyway); ESPLIT=8.
// Spill litmus: FETCH ~91MB, WRITE ~16MB regardless of VGPR count.
// Partial sums across 8 e-chunks via fp32 atomicAdd (out zeroed by memset;
// graph-capture safe).
// Data range: delay in [0,3070] => i1 <= 3071 = S-1: clamp is no-op safety.

#define A_N 4
#define E_N 128
#define S_N 3072
#define NPIX_N (512 * 256)
#define TPB 1024                   // threads per block (16 waves)
#define PXT 4                      // pixels per thread (stride-TPB)
#define TILE (TPB * PXT)           // 4096 pixels per block
#define TILES (NPIX_N / TILE)      // 32
#define ESPLIT 8                   // e-chunks
#define EPB (E_N / ESPLIT)         // 16 elements per block
#define CPA (S_N / 256)            // 12 1KB-chunks per angle row
#define CHUNKS (A_N * CPA)         // 48 chunks per buffer
#define WAVES (TPB / 64)           // 16
#define CPW (CHUNKS / WAVES)       // 3 chunks per wave

__device__ __forceinline__ void ld_lds16(const float* g, float* l) {
    // 64 lanes x 16B: global (per-lane addr) -> LDS (wave-uniform base,
    // HW adds lane*16). size must be a literal 16.
    __builtin_amdgcn_global_load_lds(
        (const __attribute__((address_space(1))) void*)g,
        (__attribute__((address_space(3))) void*)l, 16, 0, 0);
}

__global__ __launch_bounds__(TPB) void das_kernel(
    const float* __restrict__ d_tx, const float* __restrict__ d_rx,
    const float* __restrict__ apod, const float* __restrict__ rf,
    const float* __restrict__ t0,  float* __restrict__ out)
{
    __shared__ float lds_rf[2][A_N * S_N];   // 96 KB double buffer
    const int tid  = threadIdx.x;
    const int wid  = tid >> 6;
    const int lane = tid & 63;
    const int px0  = blockIdx.x * TILE + tid;   // + k*TPB for k in [0,PXT)
    const int e0   = blockIdx.y * EPB;

    // Issue async DMA of rf[a][e][:] (all 4 angles, 48KB) into buffer b.
    auto stage = [&](int b, int e) {
#pragma unroll
        for (int j = 0; j < CPW; ++j) {
            const int chunk = wid * CPW + j;        // 0..47, wave-uniform
            const int a = chunk / CPA;              // 0..3
            const int c = chunk - a * CPA;          // 0..11
            const float* g = rf + ((size_t)(a * E_N + e)) * S_N + c * 256 + lane * 4;
            float* l = &lds_rf[b][a * S_N + c * 256];
            ld_lds16(g, l);
        }
    };

    stage(0, e0);   // prologue DMA starts immediately

    float acc[A_N][PXT];
    float dta[A_N][PXT];
#pragma unroll
    for (int a = 0; a < A_N; ++a) {
        const float t0a = t0[a];
#pragma unroll
        for (int k = 0; k < PXT; ++k) {
            dta[a][k] = d_tx[a * NPIX_N + px0 + k * TPB] - t0a;
            acc[a][k] = 0.0f;
        }
    }

    // Prologue stream loads for ei=0 (complete by the barrier below).
    float ndrx[PXT], nap[PXT];
#pragma unroll
    for (int k = 0; k < PXT; ++k) {
        ndrx[k] = d_rx[(size_t)e0 * NPIX_N + px0 + k * TPB];
        nap[k]  = apod[(size_t)e0 * NPIX_N + px0 + k * TPB];
    }

    __syncthreads();   // drains vmcnt: prologue DMA + streams complete

    for (int ei = 0; ei < EPB; ++ei) {
        const int e   = e0 + ei;
        const int cur = ei & 1;

        // Current iteration's stream values (loaded last iteration).
        float drx[PXT], ap[PXT];
#pragma unroll
        for (int k = 0; k < PXT; ++k) { drx[k] = ndrx[k]; ap[k] = nap[k]; }

        // Prefetch next element: rf via DMA into the other buffer, drx/ap
        // into registers. All complete by this iteration's end barrier.
        if (ei + 1 < EPB) {
            stage(cur ^ 1, e + 1);
            const float* __restrict__ nd = d_rx + (size_t)(e + 1) * NPIX_N;
            const float* __restrict__ na = apod + (size_t)(e + 1) * NPIX_N;
#pragma unroll
            for (int k = 0; k < PXT; ++k) {
                ndrx[k] = nd[px0 + k * TPB];
                nap[k]  = na[px0 + k * TPB];
            }
        }

        // Interp: zero memory dependencies (LDS + VALU only).
        const float* __restrict__ L = lds_rf[cur];
#pragma unroll
        for (int k = 0; k < PXT; ++k) {
#pragma unroll
            for (int a = 0; a < A_N; ++a) {
                float delay = dta[a][k] + drx[k];
                float x0 = floorf(delay);
                float w  = delay - x0;
                int i0 = (int)x0;
                i0 = min(max(i0, 0), S_N - 2);   // no-op for this data; safety
                float v0 = L[a * S_N + i0];
                float v1 = L[a * S_N + i0 + 1];
                acc[a][k] += (v0 + w * (v1 - v0)) * ap[k];
            }
        }

        // Single barrier per iter: implicit s_waitcnt vmcnt(0) lgkmcnt(0)
        // = completion wait for next-buffer DMA + next-iter stream registers,
        // and release of buf[cur] for the next prefetch.
        __syncthreads();
    }

#pragma unroll
    for (int a = 0; a < A_N; ++a)
#pragma unroll
        for (int k = 0; k < PXT; ++k)
            atomicAdd(&out[a * NPIX_N + px0 + k * TPB], acc[a][k]);
}

extern "C" void kernel_launch(void* const* d_in, const int* in_sizes, int n_in,
                              void* d_out, int out_size, void* d_ws, size_t ws_size,
                              hipStream_t stream) {
    const float* d_tx = (const float*)d_in[0];
    const float* d_rx = (const float*)d_in[1];
    const float* apod = (const float*)d_in[2];
    const float* rf   = (const float*)d_in[3];
    const float* t0   = (const float*)d_in[4];
    float* out = (float*)d_out;

    hipMemsetAsync(out, 0, (size_t)out_size * sizeof(float), stream);
    dim3 grid(TILES, ESPLIT);
    das_kernel<<<grid, TPB, 0, stream>>>(d_tx, d_rx, apod, rf, t0, out);
}